// Round 1
// baseline (777.115 us; speedup 1.0000x reference)
//
#include <hip/hip_runtime.h>

// NodeToEdge: out[e, :] = (node_src[ids[0,e], :] + off_src[e, :])
//                       * (node_tgt[ids[1,e], :] + off_tgt[e, :])
// E = 300000, F = 256, fp32. Memory-bound streaming + gather kernel.
//
// Strategy (R1):
//  - wave (64 lanes) per edge row, float4 per lane (16 B/lane, 1 KiB/wave, coalesced)
//  - NON-TEMPORAL loads for off_src/off_tgt and NT store for out: these are
//    single-use streams (921 MB total) that otherwise evict the 102 MB node
//    tables from L2/L3 and force gather re-fetches from HBM.
//  - node gathers use default (cached) loads -> served from L2/L3 after first touch.
//  - persistent grid (2048 blocks = 8/CU, 32 waves/CU) + 2-edge unroll for
//    two independent id->gather chains in flight per wave.
//  - readfirstlane on wave-uniform node indices -> scalar base addressing.

#define FEAT 256

typedef float f4 __attribute__((ext_vector_type(4)));

__device__ __forceinline__ void process_edge(
    int e, int c4, int num_edges,
    const float* __restrict__ node_src,
    const float* __restrict__ node_tgt,
    const int* __restrict__ edge_ids,
    const float* __restrict__ off_src,
    const float* __restrict__ off_tgt,
    float* __restrict__ out)
{
    // Wave-uniform node indices -> force into SGPRs for scalar base addressing.
    int sid = edge_ids[e];
    int tgt = edge_ids[num_edges + e];
    sid = __builtin_amdgcn_readfirstlane(sid);
    tgt = __builtin_amdgcn_readfirstlane(tgt);

    const int eo = e * FEAT + c4;  // < 76.8M, fits int32

    // Gathers: default caching (we WANT these resident in L2/L3).
    const f4 a = *(const f4*)(node_src + sid * FEAT + c4);
    const f4 b = *(const f4*)(node_tgt + tgt * FEAT + c4);
    // Single-use streams: non-temporal (nt) -> don't pollute caches.
    const f4 oa = __builtin_nontemporal_load((const f4*)(off_src + eo));
    const f4 ob = __builtin_nontemporal_load((const f4*)(off_tgt + eo));

    f4 r;
    r.x = (a.x + oa.x) * (b.x + ob.x);
    r.y = (a.y + oa.y) * (b.y + ob.y);
    r.z = (a.z + oa.z) * (b.z + ob.z);
    r.w = (a.w + oa.w) * (b.w + ob.w);
    __builtin_nontemporal_store(r, (f4*)(out + eo));
}

__global__ __launch_bounds__(256) void node_to_edge_kernel(
    const float* __restrict__ node_src,
    const float* __restrict__ node_tgt,
    const int* __restrict__ edge_ids,   // [2, E] flat int32
    const float* __restrict__ off_src,  // [E, F]
    const float* __restrict__ off_tgt,  // [E, F]
    float* __restrict__ out,            // [E, F]
    int num_edges)
{
    const int c4 = (threadIdx.x & 63) << 2;        // float column (4 per lane)
    const int wave = threadIdx.x >> 6;             // 4 waves per block
    const int stride = gridDim.x << 2;             // edges per grid sweep

    int e = (blockIdx.x << 2) + wave;

    // 2-edge unrolled grid-stride loop: both id loads issue before either
    // gather is consumed -> two independent dependency chains in flight.
    for (; e + stride < num_edges; e += 2 * stride) {
        const int e1 = e + stride;

        int sid0 = edge_ids[e];
        int tgt0 = edge_ids[num_edges + e];
        int sid1 = edge_ids[e1];
        int tgt1 = edge_ids[num_edges + e1];
        sid0 = __builtin_amdgcn_readfirstlane(sid0);
        tgt0 = __builtin_amdgcn_readfirstlane(tgt0);
        sid1 = __builtin_amdgcn_readfirstlane(sid1);
        tgt1 = __builtin_amdgcn_readfirstlane(tgt1);

        const int eo0 = e  * FEAT + c4;
        const int eo1 = e1 * FEAT + c4;

        const f4 a0 = *(const f4*)(node_src + sid0 * FEAT + c4);
        const f4 b0 = *(const f4*)(node_tgt + tgt0 * FEAT + c4);
        const f4 a1 = *(const f4*)(node_src + sid1 * FEAT + c4);
        const f4 b1 = *(const f4*)(node_tgt + tgt1 * FEAT + c4);
        const f4 oa0 = __builtin_nontemporal_load((const f4*)(off_src + eo0));
        const f4 ob0 = __builtin_nontemporal_load((const f4*)(off_tgt + eo0));
        const f4 oa1 = __builtin_nontemporal_load((const f4*)(off_src + eo1));
        const f4 ob1 = __builtin_nontemporal_load((const f4*)(off_tgt + eo1));

        f4 r0, r1;
        r0.x = (a0.x + oa0.x) * (b0.x + ob0.x);
        r0.y = (a0.y + oa0.y) * (b0.y + ob0.y);
        r0.z = (a0.z + oa0.z) * (b0.z + ob0.z);
        r0.w = (a0.w + oa0.w) * (b0.w + ob0.w);
        r1.x = (a1.x + oa1.x) * (b1.x + ob1.x);
        r1.y = (a1.y + oa1.y) * (b1.y + ob1.y);
        r1.z = (a1.z + oa1.z) * (b1.z + ob1.z);
        r1.w = (a1.w + oa1.w) * (b1.w + ob1.w);
        __builtin_nontemporal_store(r0, (f4*)(out + eo0));
        __builtin_nontemporal_store(r1, (f4*)(out + eo1));
    }
    if (e < num_edges) {
        process_edge(e, c4, num_edges,
                     node_src, node_tgt, edge_ids, off_src, off_tgt, out);
    }
}

extern "C" void kernel_launch(void* const* d_in, const int* in_sizes, int n_in,
                              void* d_out, int out_size, void* d_ws, size_t ws_size,
                              hipStream_t stream) {
    const float* node_src = (const float*)d_in[0];
    const float* node_tgt = (const float*)d_in[1];
    const int*   edge_ids = (const int*)d_in[2];
    const float* off_src  = (const float*)d_in[3];
    const float* off_tgt  = (const float*)d_in[4];
    float* out = (float*)d_out;

    const int num_edges = in_sizes[3] / FEAT;  // off_edge_src is [E, F]

    // Persistent grid: 8 blocks/CU * 256 CUs = 2048 blocks (32 waves/CU),
    // grid-stride over edges. Cap at what's needed for small E.
    const long long waves_needed = (long long)num_edges;          // 1 wave per edge
    const long long blocks_needed = (waves_needed + 3) / 4;       // 4 waves per block
    int grid = (int)(blocks_needed < 2048 ? blocks_needed : 2048);
    if (grid < 1) grid = 1;

    node_to_edge_kernel<<<grid, 256, 0, stream>>>(
        node_src, node_tgt, edge_ids, off_src, off_tgt, out, num_edges);
}